// Round 12
// baseline (99.938 us; speedup 1.0000x reference)
//
#include <hip/hip_runtime.h>
#include <math.h>

#define BATCH 4096
#define DIM 128
#define NCLS 100
#define MARGIN 0.3f
#define NTILE 272          // upper-triangle 128x256 supertiles
#define GRID_ALL 272
#define POISON 0xAAAAAAAAu

typedef __attribute__((ext_vector_type(8))) short short8;
typedef __attribute__((ext_vector_type(4))) float f32x4;

// ---- bf16 helpers (bit-level, RNE) ----
__device__ __forceinline__ unsigned short f2bf(float f) {
    unsigned int u = __float_as_uint(f);
    unsigned int r = (u + 0x7FFFu + ((u >> 16) & 1u)) >> 16;
    return (unsigned short)r;
}
__device__ __forceinline__ float bf2f(unsigned short b) {
    return __uint_as_float(((unsigned int)b) << 16);
}

// Order-preserving encodings for NONNEGATIVE floats; identity = 0 under atomic max.
#define ENC_MAX_ID 0x80000000u   /* enc_max(0.0f) */
#define ENC_MIN_ID 0x403FFFFFu   /* enc_min(+inf) */
__device__ __forceinline__ unsigned int enc_max(float v) {
    return (__float_as_uint(v) >> 1) | 0x80000000u;
}
__device__ __forceinline__ float dec_max(unsigned int k) {
    return __uint_as_float((k & 0x7FFFFFFFu) << 1);
}
__device__ __forceinline__ unsigned int enc_min(float v) {
    return 0x7FFFFFFFu - (__float_as_uint(v) >> 1);
}
__device__ __forceinline__ float dec_min(unsigned int k) {
    return __uint_as_float((0x7FFFFFFFu - k) << 1);
}

// AGENT-scope relaxed atomic store: per-access coherent (write-through past the
// non-coherent per-XCD L2) with NO fence instructions — the R4 lesson.
__device__ __forceinline__ void st_u32(unsigned int* p, unsigned int v) {
    __hip_atomic_store(p, v, __ATOMIC_RELAXED, __HIP_MEMORY_SCOPE_AGENT);
}
__device__ __forceinline__ void st_f32(float* p, float v) {
    __hip_atomic_store(p, v, __ATOMIC_RELAXED, __HIP_MEMORY_SCOPE_AGENT);
}

// FRAGMENT-MAJOR layout: for 16-row group g, element (row%16, dim) lives at
// short-index g*2048 + (dim>>3)*128 + (row%16)*8 + (dim&7). Fragment read j
// for lane l is contiguous: g*2048 + j*512 + l*8 shorts = base + l*16 bytes.

// ONE kernel, 272 blocks x 256 threads (>=2 blocks/CU guaranteed by
// __launch_bounds__(256,2) => all 272 co-resident => spin barrier is safe).
// Phase A: blocks 0..255 convert row-group bid (emb->ebf frag-major + sq);
//          blocks 256..271 convert fc_w->wbf frag-major + zero fan region.
//          All phase-A writes are AGENT-scope atomic stores (cross-XCD visible).
// Barrier: CAS-initialized ticket (workspace is poisoned 0xAA each call).
// Phase B: all 272 blocks: upper-triangle 128x256 pairwise supertile (LDS
//          double-buffered B staging); blocks 0..255 then do CE for their group.
// Phase C: fence-free final ticket fan-in; last block reduces + writes out[0].
__global__ __launch_bounds__(256, 2) void fused_kernel(
        const float* __restrict__ emb, const int* __restrict__ labels,
        const float* __restrict__ fcw, const float* __restrict__ fcb,
        float* __restrict__ out,
        unsigned short* __restrict__ ebf, unsigned short* __restrict__ wbf,
        float* __restrict__ sq,
        unsigned int* __restrict__ maxk, unsigned int* __restrict__ mink,
        float* __restrict__ ce_sum, int* __restrict__ ticket,
        unsigned int* __restrict__ fanz, unsigned int* __restrict__ prep_ticket) {
    __shared__ float lg[16][128];
    __shared__ unsigned int colk[512];
    __shared__ unsigned short bstage[2][2048];   // 2 x 4KB B-tiles
    __shared__ int lastFlag;
    int bid = blockIdx.x, tid = threadIdx.x;
    int wave = tid >> 6, lane = tid & 63;
    int lm = lane & 15, lq = lane >> 4;

    // ================= Phase A: prep =================
    if (bid < 256) {
        unsigned int* dstg = reinterpret_cast<unsigned int*>(ebf) + bid * 1024;
        #pragma unroll
        for (int r = 0; r < 4; ++r) {
            int rowl = wave * 4 + r;
            int row = bid * 16 + rowl;
            const float2* src = reinterpret_cast<const float2*>(emb + row * DIM);
            float2 xy = src[lane];
            unsigned short b0 = f2bf(xy.x), b1 = f2bf(xy.y);
            float y0 = bf2f(b0), y1 = bf2f(b1);
            st_u32(&dstg[(lane >> 2) * 64 + rowl * 4 + (lane & 3)],
                   ((unsigned int)b1 << 16) | (unsigned int)b0);
            float acc = y0 * y0 + y1 * y1;
            #pragma unroll
            for (int off = 1; off < 64; off <<= 1) acc += __shfl_xor(acc, off, 64);
            if (lane == 0) st_f32(&sq[row], acc);
        }
    } else {
        int idx = (bid - 256) * 256 + tid;      // 0..4095
        unsigned int* wbf32 = reinterpret_cast<unsigned int*>(wbf);
        for (int t = idx; t < 7168; t += 4096) {
            int k = t * 2;                      // even short index
            int cls = k >> 7, d = k & 127;
            unsigned int packed = 0;
            if (k < NCLS * DIM)
                packed = ((unsigned int)f2bf(fcw[k + 1]) << 16) | (unsigned int)f2bf(fcw[k]);
            int dst = (cls >> 4) * 2048 + (d >> 3) * 128 + (cls & 15) * 8 + (d & 7);
            st_u32(&wbf32[dst >> 1], packed);
        }
        for (int w = idx; w < 8194; w += 4096)  // ticket_final+ce_sum+maxk+mink
            st_u32(&fanz[w], 0u);
    }
    // ---- in-kernel producer barrier (CAS-init ticket; all blocks contribute
    //      BEFORE spinning; 272 <= guaranteed-resident capacity 512) ----
    asm volatile("s_waitcnt vmcnt(0)" ::: "memory");   // drain this wave's stores
    __syncthreads();
    if (tid == 0) {
        unsigned int exp = POISON;
        __hip_atomic_compare_exchange_strong(prep_ticket, &exp, 0u,
                                             __ATOMIC_RELAXED, __ATOMIC_RELAXED,
                                             __HIP_MEMORY_SCOPE_AGENT);
        __hip_atomic_fetch_add(prep_ticket, 1u,
                               __ATOMIC_RELAXED, __HIP_MEMORY_SCOPE_AGENT);
        while (__hip_atomic_load(prep_ticket, __ATOMIC_RELAXED,
                                 __HIP_MEMORY_SCOPE_AGENT) < GRID_ALL)
            __builtin_amdgcn_s_sleep(8);
    }
    __syncthreads();   // compiler + block memory barrier; releases all waves

    // ================= Phase B: pairwise supertile =================
    {
        int c = 0, rem = bid;
        while (rem >= 2 * c + 2) { rem -= 2 * c + 2; ++c; }
        int rowgrp = rem, chunk = c;

        int rbase = rowgrp * 128 + wave * 32;
        const unsigned short* apt = ebf + (rbase >> 4) * 2048 + lane * 8;
        short8 a0 = *reinterpret_cast<const short8*>(apt);
        short8 a1 = *reinterpret_cast<const short8*>(apt + 512);
        short8 a2 = *reinterpret_cast<const short8*>(apt + 1024);
        short8 a3 = *reinterpret_cast<const short8*>(apt + 1536);
        short8 a4 = *reinterpret_cast<const short8*>(apt + 2048);
        short8 a5 = *reinterpret_cast<const short8*>(apt + 2560);
        short8 a6 = *reinterpret_cast<const short8*>(apt + 3072);
        short8 a7 = *reinterpret_cast<const short8*>(apt + 3584);

        int labr[8];
        float sqr[8];
        #pragma unroll
        for (int g = 0; g < 2; ++g)
            #pragma unroll
            for (int r = 0; r < 4; ++r) {
                labr[g * 4 + r] = labels[rbase + g * 16 + lq * 4 + r];
                sqr[g * 4 + r]  = sq[rbase + g * 16 + lq * 4 + r];
            }

        colk[tid] = 0; colk[256 + tid] = 0;

        float rmax[8], rmin[8];
        #pragma unroll
        for (int r = 0; r < 8; ++r) { rmax[r] = -INFINITY; rmin[r] = INFINITY; }

        int cbase = chunk * 256;
        const unsigned short* btile = ebf + (cbase >> 4) * 2048 + wave * 512 + lane * 8;
        uint4 breg = *reinterpret_cast<const uint4*>(btile);

        for (int ct = 0; ct < 16; ++ct) {
            *reinterpret_cast<uint4*>(&bstage[ct & 1][wave * 512 + lane * 8]) = breg;
            if (ct < 15)
                breg = *reinterpret_cast<const uint4*>(btile + (ct + 1) * 2048);
            __syncthreads();   // also covers colk init on ct=0

            const unsigned short* bb = &bstage[ct & 1][lane * 8];
            short8 b0 = *reinterpret_cast<const short8*>(bb);
            short8 b1 = *reinterpret_cast<const short8*>(bb + 512);
            short8 b2 = *reinterpret_cast<const short8*>(bb + 1024);
            short8 b3 = *reinterpret_cast<const short8*>(bb + 1536);
            f32x4 c0 = {0.f, 0.f, 0.f, 0.f};
            f32x4 c1 = {0.f, 0.f, 0.f, 0.f};
            c0 = __builtin_amdgcn_mfma_f32_16x16x32_bf16(a0, b0, c0, 0, 0, 0);
            c1 = __builtin_amdgcn_mfma_f32_16x16x32_bf16(a4, b0, c1, 0, 0, 0);
            c0 = __builtin_amdgcn_mfma_f32_16x16x32_bf16(a1, b1, c0, 0, 0, 0);
            c1 = __builtin_amdgcn_mfma_f32_16x16x32_bf16(a5, b1, c1, 0, 0, 0);
            c0 = __builtin_amdgcn_mfma_f32_16x16x32_bf16(a2, b2, c0, 0, 0, 0);
            c1 = __builtin_amdgcn_mfma_f32_16x16x32_bf16(a6, b2, c1, 0, 0, 0);
            c0 = __builtin_amdgcn_mfma_f32_16x16x32_bf16(a3, b3, c0, 0, 0, 0);
            c1 = __builtin_amdgcn_mfma_f32_16x16x32_bf16(a7, b3, c1, 0, 0, 0);

            int col = cbase + ct * 16 + lm;
            float sqc = sq[col];
            int lc = labels[col];
            float cmax = -INFINITY, cmin = INFINITY;
            #pragma unroll
            for (int r = 0; r < 4; ++r) {
                float v0 = fmaxf(fmaf(c0[r], -2.0f, sqc) + sqr[r], 0.f);
                bool s0 = (lc == labr[r]);
                rmax[r] = s0 ? fmaxf(rmax[r], v0) : rmax[r];
                rmin[r] = s0 ? rmin[r] : fminf(rmin[r], v0);
                cmax    = s0 ? fmaxf(cmax, v0) : cmax;
                cmin    = s0 ? cmin : fminf(cmin, v0);
                float v1 = fmaxf(fmaf(c1[r], -2.0f, sqc) + sqr[4 + r], 0.f);
                bool s1 = (lc == labr[4 + r]);
                rmax[4 + r] = s1 ? fmaxf(rmax[4 + r], v1) : rmax[4 + r];
                rmin[4 + r] = s1 ? rmin[4 + r] : fminf(rmin[4 + r], v1);
                cmax        = s1 ? fmaxf(cmax, v1) : cmax;
                cmin        = s1 ? cmin : fminf(cmin, v1);
            }
            cmax = fmaxf(cmax, __shfl_xor(cmax, 16, 64));
            cmax = fmaxf(cmax, __shfl_xor(cmax, 32, 64));
            cmin = fminf(cmin, __shfl_xor(cmin, 16, 64));
            cmin = fminf(cmin, __shfl_xor(cmin, 32, 64));
            if (lq == 0) {
                atomicMax(&colk[ct * 16 + lm], enc_max(fmaxf(cmax, 0.f)));
                atomicMax(&colk[256 + ct * 16 + lm], enc_min(fmaxf(cmin, 0.f)));
            }
        }
        #pragma unroll
        for (int off = 1; off < 16; off <<= 1) {
            #pragma unroll
            for (int r = 0; r < 8; ++r) {
                rmax[r] = fmaxf(rmax[r], __shfl_xor(rmax[r], off, 64));
                rmin[r] = fminf(rmin[r], __shfl_xor(rmin[r], off, 64));
            }
        }
        if (lm == 0) {
            #pragma unroll
            for (int g = 0; g < 2; ++g)
                #pragma unroll
                for (int r = 0; r < 4; ++r) {
                    int row = rbase + g * 16 + lq * 4 + r;
                    unsigned int kx = enc_max(fmaxf(rmax[g * 4 + r], 0.f));
                    unsigned int kn = enc_min(fmaxf(rmin[g * 4 + r], 0.f));
                    if (kx != ENC_MAX_ID)
                        __hip_atomic_fetch_max(&maxk[row], kx,
                                               __ATOMIC_RELAXED, __HIP_MEMORY_SCOPE_AGENT);
                    if (kn != ENC_MIN_ID)
                        __hip_atomic_fetch_max(&mink[row], kn,
                                               __ATOMIC_RELAXED, __HIP_MEMORY_SCOPE_AGENT);
                }
        }
        __syncthreads();
        {
            unsigned int kx = colk[tid], kn = colk[256 + tid];
            int col = cbase + tid;
            if (kx > ENC_MAX_ID)
                __hip_atomic_fetch_max(&maxk[col], kx,
                                       __ATOMIC_RELAXED, __HIP_MEMORY_SCOPE_AGENT);
            if (kn != 0 && kn != ENC_MIN_ID)
                __hip_atomic_fetch_max(&mink[col], kn,
                                       __ATOMIC_RELAXED, __HIP_MEMORY_SCOPE_AGENT);
        }
    }

    // ================= Phase B2: cross-entropy (blocks 0..255) =================
    if (bid < 256) {
        int R0 = bid * 16;
        __syncthreads();     // colk/bstage done; lg reuse safe
        lg[tid >> 4][112 + (tid & 15)] = -INFINITY;

        const unsigned short* apt = ebf + (R0 >> 4) * 2048 + lane * 8;
        short8 a0 = *reinterpret_cast<const short8*>(apt);
        short8 a1 = *reinterpret_cast<const short8*>(apt + 512);
        short8 a2 = *reinterpret_cast<const short8*>(apt + 1024);
        short8 a3 = *reinterpret_cast<const short8*>(apt + 1536);

        for (int t = wave * 2; t < 7 && t < wave * 2 + 2; ++t) {
            int cls = t * 16 + lm;
            const unsigned short* bp = wbf + t * 2048 + lane * 8;
            short8 b0 = *reinterpret_cast<const short8*>(bp);
            short8 b1 = *reinterpret_cast<const short8*>(bp + 512);
            short8 b2 = *reinterpret_cast<const short8*>(bp + 1024);
            short8 b3 = *reinterpret_cast<const short8*>(bp + 1536);
            f32x4 c = {0.f, 0.f, 0.f, 0.f};
            c = __builtin_amdgcn_mfma_f32_16x16x32_bf16(a0, b0, c, 0, 0, 0);
            c = __builtin_amdgcn_mfma_f32_16x16x32_bf16(a1, b1, c, 0, 0, 0);
            c = __builtin_amdgcn_mfma_f32_16x16x32_bf16(a2, b2, c, 0, 0, 0);
            c = __builtin_amdgcn_mfma_f32_16x16x32_bf16(a3, b3, c, 0, 0, 0);
            float bias = (cls < NCLS) ? fcb[cls] : -INFINITY;
            #pragma unroll
            for (int r = 0; r < 4; ++r)
                lg[lq * 4 + r][t * 16 + lm] = c[r] + bias;
        }
        __syncthreads();
        float cacc = 0.f;
        #pragma unroll
        for (int i = 0; i < 4; ++i) {
            int r = wave * 4 + i;
            float x0 = lg[r][lane], x1 = lg[r][lane + 64];
            float m = fmaxf(x0, x1);
            #pragma unroll
            for (int off = 1; off < 64; off <<= 1) m = fmaxf(m, __shfl_xor(m, off, 64));
            float s = expf(x0 - m) + expf(x1 - m);
            #pragma unroll
            for (int off = 1; off < 64; off <<= 1) s += __shfl_xor(s, off, 64);
            if (lane == 0) {
                int lab = labels[R0 + r];
                cacc += (m + logf(s)) - lg[r][lab];
            }
        }
        __syncthreads();
        if (lane == 0) lg[0][wave] = cacc;
        __syncthreads();
        if (tid == 0) {
            float bsum = lg[0][0] + lg[0][1] + lg[0][2] + lg[0][3];
            __hip_atomic_fetch_add(ce_sum, bsum,
                                   __ATOMIC_RELAXED, __HIP_MEMORY_SCOPE_AGENT);
        }
    }

    // ================= Phase C: fence-free final fan-in =================
    __syncthreads();
    asm volatile("s_waitcnt vmcnt(0)" ::: "memory");
    if (tid == 0) {
        int old = __hip_atomic_fetch_add(ticket, 1,
                                         __ATOMIC_RELAXED, __HIP_MEMORY_SCOPE_AGENT);
        lastFlag = (old == GRID_ALL - 1);
    }
    __syncthreads();
    if (lastFlag) {
        float acc = 0.f;
        #pragma unroll
        for (int rr = 0; rr < 16; ++rr) {
            int row = rr * 256 + tid;
            unsigned int kx = __hip_atomic_load(&maxk[row], __ATOMIC_RELAXED,
                                                __HIP_MEMORY_SCOPE_AGENT);
            unsigned int kn = __hip_atomic_load(&mink[row], __ATOMIC_RELAXED,
                                                __HIP_MEMORY_SCOPE_AGENT);
            float ap = sqrtf(fmaxf(dec_max(kx), 1e-12f));
            float an = sqrtf(fmaxf(dec_min(kn), 1e-12f));
            acc += fmaxf(ap - an + MARGIN, 0.f);
        }
        float* red = reinterpret_cast<float*>(lg);
        red[tid] = acc;
        __syncthreads();
        for (int s = 128; s > 0; s >>= 1) {
            if (tid < s) red[tid] += red[tid + s];
            __syncthreads();
        }
        if (tid == 0) {
            float ces = __hip_atomic_load(ce_sum, __ATOMIC_RELAXED,
                                          __HIP_MEMORY_SCOPE_AGENT);
            out[0] = (red[0] + ces) * (1.0f / BATCH);
        }
    }
}

extern "C" void kernel_launch(void* const* d_in, const int* in_sizes, int n_in,
                              void* d_out, int out_size, void* d_ws, size_t ws_size,
                              hipStream_t stream) {
    const float* emb    = (const float*)d_in[0];
    const int*   labels = (const int*)  d_in[1];
    const float* fcw    = (const float*)d_in[2];
    const float* fcb    = (const float*)d_in[3];
    float* out = (float*)d_out;

    char* ws = (char*)d_ws;
    unsigned short* ebf = (unsigned short*)(ws);                 // 1 MB (frag-major)
    unsigned short* wbf = (unsigned short*)(ws + 1048576);       // 28 KB (pad 32K)
    float* sq           = (float*)(ws + 1081344);                // 16 KB
    char* fan           = ws + 1097728;                          // zeroed in phase A
    int*   ticket       = (int*)(fan);                           // 4 B  (fanz[0])
    float* ce_sum       = (float*)(fan + 4);                     // 4 B  (fanz[1])
    unsigned int* maxk  = (unsigned int*)(fan + 8);              // 16 KB
    unsigned int* mink  = (unsigned int*)(fan + 8 + 16384);      // 16 KB
    unsigned int* prep_ticket = (unsigned int*)(fan + 8 + 32768);// 4 B (CAS-init)

    fused_kernel<<<GRID_ALL, 256, 0, stream>>>(
        emb, labels, fcw, fcb, out, ebf, wbf, sq,
        maxk, mink, ce_sum, ticket, (unsigned int*)fan, prep_ticket);
}